// Round 6
// baseline (886.765 us; speedup 1.0000x reference)
//
#include <hip/hip_runtime.h>
#include <hip/hip_cooperative_groups.h>
#include <stdint.h>

namespace cg = cooperative_groups;

#define A_N 9
#define H_N 50
#define W_N 76
#define HW_N (H_N * W_N)      // 3800
#define N_PROP (A_N * HW_N)   // 34200
#define B_N 4
#define PRE_NMS 4000
#define POST_NMS 300
#define NMS_TH 0.7f
#define SORT_N 4096
#define MASK_WORDS 64
#define CAND_MAX 5120
#define NBINS 4096
#define GRID_B 256
#define BLOCK_T 256
#define GT (GRID_B * BLOCK_T)   // 65536 threads

typedef unsigned long long u64;

__device__ inline u64 rl64(u64 v, int src) {
    unsigned lo = (unsigned)__builtin_amdgcn_readlane((int)(unsigned)(v & 0xFFFFFFFFull), src);
    unsigned hi = (unsigned)__builtin_amdgcn_readlane((int)(unsigned)(v >> 32), src);
    return ((u64)hi << 32) | lo;
}
__device__ inline float rlf(float v, int src) {
    return __int_as_float(__builtin_amdgcn_readlane(__float_as_int(v), src));
}

// ===========================================================================
// ONE cooperative kernel: zero -> decode+hist -> findT -> compact -> rank ->
// iou-mask(rowmaj) -> group-tile NMS scan (LDS double-buffered speculation).
// ===========================================================================
__global__ __launch_bounds__(BLOCK_T, 1) void fused_proposal_kernel(
    const float* __restrict__ scores,
    const float* __restrict__ deltas,
    const float* __restrict__ im_info,
    const float* __restrict__ anchors,
    float* __restrict__ out,
    float4* __restrict__ boxes,
    u64* __restrict__ keys,
    unsigned* __restrict__ ghist,
    unsigned* __restrict__ cnt,
    int* __restrict__ Tbuf,
    u64* __restrict__ cand,
    float4* __restrict__ sortedBoxes,
    u64* __restrict__ rowmaj) {
#pragma clang fp contract(off)
    __shared__ u64 sbuf[8192];  // 64 KB, re-used per phase
    cg::grid_group grid = cg::this_grid();
    const int tid = threadIdx.x;
    const int lane = tid & 63;
    const int wid = tid >> 6;
    const int gtid = blockIdx.x * BLOCK_T + tid;

    // ---- phase 0: zero hist + counters -----------------------------------
    for (int i = gtid; i < B_N * NBINS; i += GT) ghist[i] = 0u;
    if (gtid < B_N) cnt[gtid] = 0u;
    grid.sync();

    // ---- phase 1: decode + keys + histogram ------------------------------
    for (int i = gtid; i < B_N * N_PROP; i += GT) {
        int b = i / N_PROP;
        int r = i - b * N_PROP;
        int a = r / HW_N;          // fixed across a wave
        int hw = r - a * HW_N;     // consecutive across lanes -> coalesced
        int hy = hw / W_N;
        int wx = hw - hy * W_N;

        float sx = (float)wx * 16.0f;
        float sy = (float)hy * 16.0f;
        float ax1 = anchors[a * 4 + 0] + sx;
        float ay1 = anchors[a * 4 + 1] + sy;
        float ax2 = anchors[a * 4 + 2] + sx;
        float ay2 = anchors[a * 4 + 3] + sy;
        float aw = ax2 - ax1 + 1.0f;
        float ah = ay2 - ay1 + 1.0f;
        float cx = ax1 + 0.5f * aw;
        float cy = ay1 + 0.5f * ah;

        const float* db = deltas + ((size_t)b * 36 + (size_t)a * 4) * HW_N + hw;
        float d0 = db[0];
        float d1 = db[HW_N];
        float d2 = db[2 * HW_N];
        float d3 = db[3 * HW_N];

        float pcx = d0 * aw + cx;
        float pcy = d1 * ah + cy;
        float pw  = expf(d2) * aw;
        float ph  = expf(d3) * ah;

        float x1 = pcx - 0.5f * pw;
        float y1 = pcy - 0.5f * ph;
        float x2 = pcx + 0.5f * pw;
        float y2 = pcy + 0.5f * ph;

        float xhi = im_info[b * 3 + 1] - 1.0f;
        float yhi = im_info[b * 3 + 0] - 1.0f;
        x1 = fminf(fmaxf(x1, 0.0f), xhi);
        y1 = fminf(fmaxf(y1, 0.0f), yhi);
        x2 = fminf(fmaxf(x2, 0.0f), xhi);
        y2 = fminf(fmaxf(y2, 0.0f), yhi);

        boxes[i] = make_float4(x1, y1, x2, y2);  // a-major layout

        float s = scores[((size_t)b * A_N + a) * HW_N + hw];
        unsigned f = __float_as_uint(s);
        unsigned sk = f ^ ((f & 0x80000000u) ? 0xFFFFFFFFu : 0x80000000u);
        unsigned n_ref = (unsigned)(hw * A_N + a);   // reference index for tie-break
        u64 key = ((u64)sk << 32) | (unsigned)(~n_ref);
        keys[i] = key;
        atomicAdd(&ghist[b * NBINS + (unsigned)(key >> 52)], 1u);
    }
    grid.sync();

    // ---- phase 2: per-image threshold bucket T (wave 0 of blocks 0..3) ---
    if (blockIdx.x < B_N && wid == 0) {
        int b = blockIdx.x;
        unsigned s = 0;
        const unsigned* H = ghist + b * NBINS;
#pragma unroll 8
        for (int j = 0; j < 64; ++j) s += H[lane * 64 + j];
        for (int d = 1; d < 64; d <<= 1) {
            unsigned t = (unsigned)__shfl_down((int)s, d);
            if (lane + d < 64) s += t;
        }
        unsigned long long bal = __ballot(s >= PRE_NMS);
        int gstar = 63 - __builtin_clzll(bal);
        unsigned after = (gstar < 63) ? (unsigned)__builtin_amdgcn_readlane((int)s, gstar + 1) : 0u;
        unsigned R = PRE_NMS - after;
        unsigned s2 = H[gstar * 64 + lane];
        for (int d = 1; d < 64; d <<= 1) {
            unsigned t = (unsigned)__shfl_down((int)s2, d);
            if (lane + d < 64) s2 += t;
        }
        unsigned long long bal2 = __ballot(s2 >= R);
        int j = 63 - __builtin_clzll(bal2);
        if (lane == 0) Tbuf[b] = gstar * 64 + j;
    }
    grid.sync();

    // ---- phase 3: compact candidates (wave-aggregated atomic) ------------
    for (int b = 0; b < B_N; ++b) {
        int T = Tbuf[b];
        for (int n = gtid; n < N_PROP; n += GT) {
            u64 k = keys[(size_t)b * N_PROP + n];
            bool pred = ((int)(unsigned)(k >> 52) >= T);
            unsigned long long m = __ballot(pred);
            if (m) {
                int lead = __ffsll(m) - 1;
                unsigned base = 0;
                if (lane == lead) base = atomicAdd(&cnt[b], (unsigned)__popcll(m));
                base = (unsigned)__shfl((int)base, lead);
                if (pred) {
                    unsigned pos = base + (unsigned)__popcll(m & ((1ull << lane) - 1ull));
                    if (pos < CAND_MAX) cand[(size_t)b * CAND_MAX + pos] = k;
                }
            }
        }
    }
    grid.sync();

    // ---- phase 4: exact rank by pairwise count + scatter -----------------
    {
        u64* skl = sbuf;  // 256 u64 tile
        const int SLICES = (CAND_MAX / 64) * B_N;  // 320
        for (int s = blockIdx.x; s < SLICES; s += GRID_B) {
            int b = s / (CAND_MAX / 64);
            int s_in = s - b * (CAND_MAX / 64);
            int ci = s_in * 64 + (tid >> 2);
            int q = tid & 3;
            int mc = (int)min(cnt[b], (unsigned)CAND_MAX);
            u64 my = (ci < mc) ? cand[(size_t)b * CAND_MAX + ci] : 0ull;
            int rank = 0;
            int nt = (mc + 255) >> 8;
            for (int t = 0; t < nt; ++t) {
                int j = t * 256 + tid;
                skl[tid] = (j < mc) ? cand[(size_t)b * CAND_MAX + j] : 0ull;
                __syncthreads();
#pragma unroll 16
                for (int c = 0; c < 64; ++c) {
                    int cc = q * 64 + ((c + q * 17) & 63);
                    rank += (skl[cc] > my) ? 1 : 0;
                }
                __syncthreads();
            }
            rank += __shfl_xor(rank, 1);
            rank += __shfl_xor(rank, 2);
            if (q == 0 && ci < mc && rank < PRE_NMS) {
                unsigned n_ref = ~(unsigned)(my & 0xFFFFFFFFull);
                unsigned a = n_ref % A_N;
                unsigned hw = n_ref / A_N;
                sortedBoxes[(size_t)b * SORT_N + rank] =
                    boxes[(size_t)b * N_PROP + a * HW_N + hw];
            }
            if (q == 1 && ci >= PRE_NMS && ci < SORT_N)
                sortedBoxes[(size_t)b * SORT_N + ci] = make_float4(0.f, 0.f, 0.f, 0.f);
        }
    }
    grid.sync();

    // ---- phase 5: IoU suppression bitmask -> row-major, upper tri --------
    {
        int wgid = blockIdx.x * 4 + wid;  // 1024 waves
        for (int t = wgid; t < B_N * 64 * 64; t += GRID_B * 4) {
            int b = t >> 12;
            int rc = (t >> 6) & 63;
            int cc = t & 63;
            if (cc < rc) continue;  // wave-uniform skip
            int r = rc * 64 + lane;
            float4 rb = sortedBoxes[(size_t)b * SORT_N + r];
            float4 cbl = sortedBoxes[(size_t)b * SORT_N + cc * 64 + lane];
            float rarea = (rb.z - rb.x) * (rb.w - rb.y);
            u64 word = 0ull;
#pragma unroll 16
            for (int c = 0; c < 64; ++c) {
                float cx1 = rlf(cbl.x, c);
                float cy1 = rlf(cbl.y, c);
                float cx2 = rlf(cbl.z, c);
                float cy2 = rlf(cbl.w, c);
                float carea = (cx2 - cx1) * (cy2 - cy1);
                float ltx = fmaxf(rb.x, cx1);
                float lty = fmaxf(rb.y, cy1);
                float rbx = fminf(rb.z, cx2);
                float rby = fminf(rb.w, cy2);
                float iw = fmaxf(rbx - ltx, 0.0f);
                float ih = fmaxf(rby - lty, 0.0f);
                float inter = iw * ih;
                float iou = inter / (rarea + carea - inter + 1e-9f);
                int j = cc * 64 + c;
                if (iou > NMS_TH && j > r) word |= (1ull << c);
            }
            rowmaj[((size_t)b * SORT_N + r) * MASK_WORDS + cc] = word;
        }
    }
    grid.sync();

    // ---- phase 6: group-tile greedy NMS scan (blocks 0..3 only) ----------
    if (blockIdx.x < B_N) {
        int b = blockIdx.x;
        const u64* Rm = rowmaj + (size_t)b * SORT_N * MASK_WORDS;
        u64* B0 = sbuf;         // group tile, rotated layout, 32 KB
        u64* B1 = sbuf + 4096;  // double buffer

        // initial prefetch: group 0 rows into B0 (all 4 waves)
        for (int r = wid; r < 64; r += 4)
            B0[r * 64 + ((lane + r) & 63)] = Rm[(size_t)r * MASK_WORDS + lane];
        __syncthreads();

        u64 rem = 0ull;                       // lane w: removed bits of group w
        int k0 = 0, k1 = 0, k2 = 0, k3 = 0, k4 = 0;
        int kcnt = 0;
        bool done = false;

        for (int g = 0; g < 64; ++g) {
            u64* Bc = (g & 1) ? B1 : B0;
            u64* Bn = (g & 1) ? B0 : B1;
            if (wid == 0) {
                if (!done) {
                    u64 Dg = Bc[lane * 64 + ((g + lane) & 63)];  // row lane, word g
                    u64 cur = rl64(rem, g);
                    u64 pending = ~cur;
                    u64 alive = 0ull;
                    while (pending) {
                        int bit = __builtin_ctzll(pending);
                        int i = (g << 6) + bit;
                        if (lane == (kcnt & 63)) {
                            switch (kcnt >> 6) {
                                case 0: k0 = i; break;
                                case 1: k1 = i; break;
                                case 2: k2 = i; break;
                                case 3: k3 = i; break;
                                default: k4 = i; break;
                            }
                        }
                        ++kcnt;
                        alive |= 1ull << bit;
                        if (kcnt == POST_NMS) { done = true; break; }
                        u64 d = rl64(Dg, bit);
                        pending &= ~(d | (1ull << bit));
                    }
                    // OR kept rows (LDS, conflict-free rotated reads)
                    u64 am = alive;
                    while (am) {
                        int i = __builtin_ctzll(am);
                        am &= am - 1;
                        rem |= Bc[i * 64 + ((lane + i) & 63)];
                    }
                }
            } else if (g < 63) {
                int gn = g + 1;
                for (int r = wid - 1; r < 64; r += 3) {
                    if (lane >= gn)  // only upper-triangle words are valid
                        Bn[r * 64 + ((lane + r) & 63)] =
                            Rm[((size_t)(gn << 6) + r) * MASK_WORDS + lane];
                }
            }
            __syncthreads();
        }

        // output (wave 0): row r handled by lane r&63, slot r>>6
        if (wid == 0) {
#pragma unroll
            for (int j = 0; j < 5; ++j) {
                int r = (j << 6) + lane;
                if (r < POST_NMS) {
                    int idx = (j == 0) ? k0 : (j == 1) ? k1 : (j == 2) ? k2
                              : (j == 3) ? k3 : k4;
                    float4 bx = make_float4(0.f, 0.f, 0.f, 0.f);
                    if (r < kcnt) bx = sortedBoxes[(size_t)b * SORT_N + idx];
                    float* o = out + ((size_t)b * POST_NMS + r) * 5;
                    o[0] = (float)b;
                    o[1] = bx.x;
                    o[2] = bx.y;
                    o[3] = bx.z;
                    o[4] = bx.w;
                }
            }
        }
    }
}

// ---------------------------------------------------------------------------
extern "C" void kernel_launch(void* const* d_in, const int* in_sizes, int n_in,
                              void* d_out, int out_size, void* d_ws, size_t ws_size,
                              hipStream_t stream) {
    const float* scores  = (const float*)d_in[0];
    const float* deltas  = (const float*)d_in[1];
    const float* im_info = (const float*)d_in[2];
    const float* anchors = (const float*)d_in[3];
    float* out = (float*)d_out;

    char* ws = (char*)d_ws;
    size_t off = 0;
    float4* sortedBoxes = (float4*)(ws + off);
    off += (size_t)B_N * SORT_N * sizeof(float4);
    off = (off + 255) & ~(size_t)255;
    u64* rowmaj = (u64*)(ws + off);
    off += (size_t)B_N * SORT_N * MASK_WORDS * sizeof(u64);
    off = (off + 255) & ~(size_t)255;
    float4* boxes = (float4*)(ws + off);
    off += (size_t)B_N * N_PROP * sizeof(float4);
    off = (off + 255) & ~(size_t)255;
    u64* keys = (u64*)(ws + off);
    off += (size_t)B_N * N_PROP * sizeof(u64);
    off = (off + 255) & ~(size_t)255;
    u64* cand = (u64*)(ws + off);
    off += (size_t)B_N * CAND_MAX * sizeof(u64);
    off = (off + 255) & ~(size_t)255;
    unsigned* ghist = (unsigned*)(ws + off);
    off += (size_t)B_N * NBINS * sizeof(unsigned);
    unsigned* cnt = (unsigned*)(ws + off);
    off += (size_t)B_N * sizeof(unsigned);
    off = (off + 255) & ~(size_t)255;
    int* Tbuf = (int*)(ws + off);
    off += (size_t)B_N * sizeof(int);
    // ~11.8 MB total

    void* args[] = {
        (void*)&scores, (void*)&deltas, (void*)&im_info, (void*)&anchors,
        (void*)&out, (void*)&boxes, (void*)&keys, (void*)&ghist,
        (void*)&cnt, (void*)&Tbuf, (void*)&cand, (void*)&sortedBoxes,
        (void*)&rowmaj
    };
    hipLaunchCooperativeKernel((const void*)fused_proposal_kernel,
                               dim3(GRID_B), dim3(BLOCK_T), args, 0, stream);
}

// Round 7
// 578.374 us; speedup vs baseline: 1.5332x; 1.5332x over previous
//
#include <hip/hip_runtime.h>
#include <hip/hip_cooperative_groups.h>
#include <stdint.h>

namespace cg = cooperative_groups;

#define A_N 9
#define H_N 50
#define W_N 76
#define HW_N (H_N * W_N)      // 3800
#define N_PROP (A_N * HW_N)   // 34200
#define B_N 4
#define PRE_NMS 4000
#define POST_NMS 300
#define NMS_TH 0.7f
#define SORT_N 4096
#define MASK_WORDS 64
#define CAND_MAX 5120
#define NBINS 4096
#define GRID_B 256
#define BLOCK_T 256
#define GT (GRID_B * BLOCK_T)   // 65536 threads

typedef unsigned long long u64;

__device__ inline u64 rl64(u64 v, int src) {
    unsigned lo = (unsigned)__builtin_amdgcn_readlane((int)(unsigned)(v & 0xFFFFFFFFull), src);
    unsigned hi = (unsigned)__builtin_amdgcn_readlane((int)(unsigned)(v >> 32), src);
    return ((u64)hi << 32) | lo;
}
__device__ inline float rlf(float v, int src) {
    return __int_as_float(__builtin_amdgcn_readlane(__float_as_int(v), src));
}

// Load 22 rows (r0..r0+21) of a 64-row x 64-word tile from global into LDS.
// 22 NAMED u64 locals (never an array -> never spilled via SROA failure):
// 22 independent global_load_dwordx2 in flight together, one drain, 22 stores.
__device__ __forceinline__ void fetch_rows(const u64* __restrict__ src,
                                           u64* __restrict__ dst,
                                           int r0, int lane) {
    const u64* s = src + ((size_t)r0 << 6) + lane;
    u64 v00 = s[0 << 6],  v01 = s[1 << 6],  v02 = s[2 << 6],  v03 = s[3 << 6];
    u64 v04 = s[4 << 6],  v05 = s[5 << 6],  v06 = s[6 << 6],  v07 = s[7 << 6];
    u64 v08 = s[8 << 6],  v09 = s[9 << 6],  v10 = s[10 << 6], v11 = s[11 << 6];
    u64 v12 = s[12 << 6], v13 = s[13 << 6], v14 = s[14 << 6], v15 = s[15 << 6];
    u64 v16 = s[16 << 6], v17 = s[17 << 6], v18 = s[18 << 6], v19 = s[19 << 6];
    u64 v20 = s[20 << 6], v21 = s[21 << 6];
    u64* d = dst + (r0 << 6) + lane;
    d[0 << 6] = v00;  d[1 << 6] = v01;  d[2 << 6] = v02;  d[3 << 6] = v03;
    d[4 << 6] = v04;  d[5 << 6] = v05;  d[6 << 6] = v06;  d[7 << 6] = v07;
    d[8 << 6] = v08;  d[9 << 6] = v09;  d[10 << 6] = v10; d[11 << 6] = v11;
    d[12 << 6] = v12; d[13 << 6] = v13; d[14 << 6] = v14; d[15 << 6] = v15;
    d[16 << 6] = v16; d[17 << 6] = v17; d[18 << 6] = v18; d[19 << 6] = v19;
    d[20 << 6] = v20; d[21 << 6] = v21;
}

// ===========================================================================
// ONE cooperative kernel: zero -> decode+hist -> findT -> compact -> rank ->
// iou-mask(rowmaj+diag) -> group-tile NMS scan (LDS dbuf, batched staging).
// ===========================================================================
__global__ __launch_bounds__(BLOCK_T, 1) void fused_proposal_kernel(
    const float* __restrict__ scores,
    const float* __restrict__ deltas,
    const float* __restrict__ im_info,
    const float* __restrict__ anchors,
    float* __restrict__ out,
    float4* __restrict__ boxes,
    u64* __restrict__ keys,
    unsigned* __restrict__ ghist,
    unsigned* __restrict__ cnt,
    int* __restrict__ Tbuf,
    u64* __restrict__ cand,
    float4* __restrict__ sortedBoxes,
    u64* __restrict__ rowmaj,
    u64* __restrict__ diagArr) {
#pragma clang fp contract(off)
    __shared__ u64 sbuf[8192];  // 64 KB, re-used per phase
    cg::grid_group grid = cg::this_grid();
    const int tid = threadIdx.x;
    const int lane = tid & 63;
    const int wid = tid >> 6;
    const int gtid = blockIdx.x * BLOCK_T + tid;

    // ---- phase 0: zero hist + counters -----------------------------------
    for (int i = gtid; i < B_N * NBINS; i += GT) ghist[i] = 0u;
    if (gtid < B_N) cnt[gtid] = 0u;
    grid.sync();

    // ---- phase 1: decode + keys + histogram ------------------------------
    for (int i = gtid; i < B_N * N_PROP; i += GT) {
        int b = i / N_PROP;
        int r = i - b * N_PROP;
        int a = r / HW_N;          // fixed across a wave
        int hw = r - a * HW_N;     // consecutive across lanes -> coalesced
        int hy = hw / W_N;
        int wx = hw - hy * W_N;

        float sx = (float)wx * 16.0f;
        float sy = (float)hy * 16.0f;
        float ax1 = anchors[a * 4 + 0] + sx;
        float ay1 = anchors[a * 4 + 1] + sy;
        float ax2 = anchors[a * 4 + 2] + sx;
        float ay2 = anchors[a * 4 + 3] + sy;
        float aw = ax2 - ax1 + 1.0f;
        float ah = ay2 - ay1 + 1.0f;
        float cx = ax1 + 0.5f * aw;
        float cy = ay1 + 0.5f * ah;

        const float* db = deltas + ((size_t)b * 36 + (size_t)a * 4) * HW_N + hw;
        float d0 = db[0];
        float d1 = db[HW_N];
        float d2 = db[2 * HW_N];
        float d3 = db[3 * HW_N];

        float pcx = d0 * aw + cx;
        float pcy = d1 * ah + cy;
        float pw  = expf(d2) * aw;
        float ph  = expf(d3) * ah;

        float x1 = pcx - 0.5f * pw;
        float y1 = pcy - 0.5f * ph;
        float x2 = pcx + 0.5f * pw;
        float y2 = pcy + 0.5f * ph;

        float xhi = im_info[b * 3 + 1] - 1.0f;
        float yhi = im_info[b * 3 + 0] - 1.0f;
        x1 = fminf(fmaxf(x1, 0.0f), xhi);
        y1 = fminf(fmaxf(y1, 0.0f), yhi);
        x2 = fminf(fmaxf(x2, 0.0f), xhi);
        y2 = fminf(fmaxf(y2, 0.0f), yhi);

        boxes[i] = make_float4(x1, y1, x2, y2);  // a-major layout

        float s = scores[((size_t)b * A_N + a) * HW_N + hw];
        unsigned f = __float_as_uint(s);
        unsigned sk = f ^ ((f & 0x80000000u) ? 0xFFFFFFFFu : 0x80000000u);
        unsigned n_ref = (unsigned)(hw * A_N + a);   // reference index (tie-break)
        u64 key = ((u64)sk << 32) | (unsigned)(~n_ref);
        keys[i] = key;
        atomicAdd(&ghist[b * NBINS + (unsigned)(key >> 52)], 1u);
    }
    grid.sync();

    // ---- phase 2: per-image threshold bucket T (wave 0 of blocks 0..3) ---
    if (blockIdx.x < B_N && wid == 0) {
        int b = blockIdx.x;
        unsigned s = 0;
        const unsigned* H = ghist + b * NBINS;
#pragma unroll 8
        for (int j = 0; j < 64; ++j) s += H[lane * 64 + j];
        for (int d = 1; d < 64; d <<= 1) {
            unsigned t = (unsigned)__shfl_down((int)s, d);
            if (lane + d < 64) s += t;
        }
        unsigned long long bal = __ballot(s >= PRE_NMS);
        int gstar = 63 - __builtin_clzll(bal);
        unsigned after = (gstar < 63) ? (unsigned)__builtin_amdgcn_readlane((int)s, gstar + 1) : 0u;
        unsigned R = PRE_NMS - after;
        unsigned s2 = H[gstar * 64 + lane];
        for (int d = 1; d < 64; d <<= 1) {
            unsigned t = (unsigned)__shfl_down((int)s2, d);
            if (lane + d < 64) s2 += t;
        }
        unsigned long long bal2 = __ballot(s2 >= R);
        int j = 63 - __builtin_clzll(bal2);
        if (lane == 0) Tbuf[b] = gstar * 64 + j;
    }
    grid.sync();

    // ---- phase 3: compact candidates (wave-aggregated atomic) ------------
    for (int b = 0; b < B_N; ++b) {
        int T = Tbuf[b];
        for (int n = gtid; n < N_PROP; n += GT) {
            u64 k = keys[(size_t)b * N_PROP + n];
            bool pred = ((int)(unsigned)(k >> 52) >= T);
            unsigned long long m = __ballot(pred);
            if (m) {
                int lead = __ffsll(m) - 1;
                unsigned base = 0;
                if (lane == lead) base = atomicAdd(&cnt[b], (unsigned)__popcll(m));
                base = (unsigned)__shfl((int)base, lead);
                if (pred) {
                    unsigned pos = base + (unsigned)__popcll(m & ((1ull << lane) - 1ull));
                    if (pos < CAND_MAX) cand[(size_t)b * CAND_MAX + pos] = k;
                }
            }
        }
    }
    grid.sync();

    // ---- phase 4: exact rank by pairwise count + scatter -----------------
    {
        u64* skl = sbuf;  // 256 u64 tile
        const int SLICES = (CAND_MAX / 64) * B_N;  // 320
        for (int s = blockIdx.x; s < SLICES; s += GRID_B) {
            int b = s / (CAND_MAX / 64);
            int s_in = s - b * (CAND_MAX / 64);
            int ci = s_in * 64 + (tid >> 2);
            int q = tid & 3;
            int mc = (int)min(cnt[b], (unsigned)CAND_MAX);
            u64 my = (ci < mc) ? cand[(size_t)b * CAND_MAX + ci] : 0ull;
            int rank = 0;
            int nt = (mc + 255) >> 8;
            for (int t = 0; t < nt; ++t) {
                int j = t * 256 + tid;
                skl[tid] = (j < mc) ? cand[(size_t)b * CAND_MAX + j] : 0ull;
                __syncthreads();
#pragma unroll 16
                for (int c = 0; c < 64; ++c) {
                    int cc = q * 64 + ((c + q * 17) & 63);
                    rank += (skl[cc] > my) ? 1 : 0;
                }
                __syncthreads();
            }
            rank += __shfl_xor(rank, 1);
            rank += __shfl_xor(rank, 2);
            if (q == 0 && ci < mc && rank < PRE_NMS) {
                unsigned n_ref = ~(unsigned)(my & 0xFFFFFFFFull);
                unsigned a = n_ref % A_N;
                unsigned hw = n_ref / A_N;
                sortedBoxes[(size_t)b * SORT_N + rank] =
                    boxes[(size_t)b * N_PROP + a * HW_N + hw];
            }
            if (q == 1 && ci >= PRE_NMS && ci < SORT_N)
                sortedBoxes[(size_t)b * SORT_N + ci] = make_float4(0.f, 0.f, 0.f, 0.f);
        }
    }
    grid.sync();

    // ---- phase 5: IoU bitmask -> row-major + diagonal array, upper tri ---
    {
        int wgid = blockIdx.x * 4 + wid;  // 1024 waves
        for (int t = wgid; t < B_N * 64 * 64; t += GRID_B * 4) {
            int b = t >> 12;
            int rc = (t >> 6) & 63;
            int cc = t & 63;
            if (cc < rc) continue;  // wave-uniform skip
            int r = rc * 64 + lane;
            float4 rb = sortedBoxes[(size_t)b * SORT_N + r];
            float4 cbl = sortedBoxes[(size_t)b * SORT_N + cc * 64 + lane];
            float rarea = (rb.z - rb.x) * (rb.w - rb.y);
            u64 word = 0ull;
#pragma unroll 16
            for (int c = 0; c < 64; ++c) {
                float cx1 = rlf(cbl.x, c);
                float cy1 = rlf(cbl.y, c);
                float cx2 = rlf(cbl.z, c);
                float cy2 = rlf(cbl.w, c);
                float carea = (cx2 - cx1) * (cy2 - cy1);
                float ltx = fmaxf(rb.x, cx1);
                float lty = fmaxf(rb.y, cy1);
                float rbx = fminf(rb.z, cx2);
                float rby = fminf(rb.w, cy2);
                float iw = fmaxf(rbx - ltx, 0.0f);
                float ih = fmaxf(rby - lty, 0.0f);
                float inter = iw * ih;
                float iou = inter / (rarea + carea - inter + 1e-9f);
                int j = cc * 64 + c;
                if (iou > NMS_TH && j > r) word |= (1ull << c);
            }
            rowmaj[((size_t)b * SORT_N + r) * MASK_WORDS + cc] = word;
            if (rc == cc)
                diagArr[((size_t)b << 12) + (rc << 6) + lane] = word;
        }
    }
    grid.sync();

    // ---- phase 6: group-tile greedy NMS scan (blocks 0..3) ---------------
    // Wave 0 resolves group g from LDS tile + register-prefetched diag;
    // waves 1..3 stage group g+1's full 32KB row-tile with batched loads.
    if (blockIdx.x < B_N) {
        const int b = blockIdx.x;
        const u64* Rm = rowmaj + (size_t)b * SORT_N * MASK_WORDS;
        const u64* Dga = diagArr + ((size_t)b << 12);
        u64* B0 = sbuf;
        u64* B1 = sbuf + 4096;

        u64 nDiag = 0ull;
        if (wid == 0) nDiag = Dga[lane];
        else fetch_rows(Rm, B0, (wid - 1) * 21, lane);  // rows 0-21,21-42,42-63
        __syncthreads();

        u64 rem = 0ull;  // lane w: removed bits of group w
        int k0 = 0, k1 = 0, k2 = 0, k3 = 0, k4 = 0;
        int kcnt = 0;
        bool done = false;

        for (int g = 0; g < 64; ++g) {
            u64* Bc = (g & 1) ? B1 : B0;
            u64* Bn = (g & 1) ? B0 : B1;
            if (wid == 0) {
                u64 Dg = nDiag;
                if (g < 63) nDiag = Dga[((g + 1) << 6) + lane];
                if (!done) {
                    u64 cur = rl64(rem, g);
                    u64 pending = ~cur;
                    u64 alive = 0ull;
                    while (pending) {
                        int bit = __builtin_ctzll(pending);
                        int i = (g << 6) + bit;
                        if (lane == (kcnt & 63)) {
                            switch (kcnt >> 6) {
                                case 0: k0 = i; break;
                                case 1: k1 = i; break;
                                case 2: k2 = i; break;
                                case 3: k3 = i; break;
                                default: k4 = i; break;
                            }
                        }
                        ++kcnt;
                        alive |= 1ull << bit;
                        if (kcnt == POST_NMS) { done = true; break; }
                        u64 d = rl64(Dg, bit);
                        pending &= ~(d | (1ull << bit));
                    }
                    u64 am = alive;
                    while (am) {
                        int i = __builtin_ctzll(am);
                        am &= am - 1;
                        rem |= Bc[(i << 6) + lane];
                    }
                }
            } else if (g < 63) {
                fetch_rows(Rm + ((size_t)(g + 1) << 12), Bn, (wid - 1) * 21, lane);
            }
            __syncthreads();
        }

        // output (wave 0): row r handled by lane r&63, slot r>>6
        if (wid == 0) {
#pragma unroll
            for (int j = 0; j < 5; ++j) {
                int r = (j << 6) + lane;
                if (r < POST_NMS) {
                    int idx = (j == 0) ? k0 : (j == 1) ? k1 : (j == 2) ? k2
                              : (j == 3) ? k3 : k4;
                    float4 bx = make_float4(0.f, 0.f, 0.f, 0.f);
                    if (r < kcnt) bx = sortedBoxes[(size_t)b * SORT_N + idx];
                    float* o = out + ((size_t)b * POST_NMS + r) * 5;
                    o[0] = (float)b;
                    o[1] = bx.x;
                    o[2] = bx.y;
                    o[3] = bx.z;
                    o[4] = bx.w;
                }
            }
        }
    }
}

// ---------------------------------------------------------------------------
extern "C" void kernel_launch(void* const* d_in, const int* in_sizes, int n_in,
                              void* d_out, int out_size, void* d_ws, size_t ws_size,
                              hipStream_t stream) {
    const float* scores  = (const float*)d_in[0];
    const float* deltas  = (const float*)d_in[1];
    const float* im_info = (const float*)d_in[2];
    const float* anchors = (const float*)d_in[3];
    float* out = (float*)d_out;

    char* ws = (char*)d_ws;
    size_t off = 0;
    float4* sortedBoxes = (float4*)(ws + off);
    off += (size_t)B_N * SORT_N * sizeof(float4);
    off = (off + 255) & ~(size_t)255;
    u64* rowmaj = (u64*)(ws + off);
    off += (size_t)B_N * SORT_N * MASK_WORDS * sizeof(u64);
    off = (off + 255) & ~(size_t)255;
    u64* diagArr = (u64*)(ws + off);
    off += (size_t)B_N * SORT_N * sizeof(u64);
    off = (off + 255) & ~(size_t)255;
    float4* boxes = (float4*)(ws + off);
    off += (size_t)B_N * N_PROP * sizeof(float4);
    off = (off + 255) & ~(size_t)255;
    u64* keys = (u64*)(ws + off);
    off += (size_t)B_N * N_PROP * sizeof(u64);
    off = (off + 255) & ~(size_t)255;
    u64* cand = (u64*)(ws + off);
    off += (size_t)B_N * CAND_MAX * sizeof(u64);
    off = (off + 255) & ~(size_t)255;
    unsigned* ghist = (unsigned*)(ws + off);
    off += (size_t)B_N * NBINS * sizeof(unsigned);
    unsigned* cnt = (unsigned*)(ws + off);
    off += (size_t)B_N * sizeof(unsigned);
    off = (off + 255) & ~(size_t)255;
    int* Tbuf = (int*)(ws + off);
    off += (size_t)B_N * sizeof(int);
    // ~12 MB total

    void* args[] = {
        (void*)&scores, (void*)&deltas, (void*)&im_info, (void*)&anchors,
        (void*)&out, (void*)&boxes, (void*)&keys, (void*)&ghist,
        (void*)&cnt, (void*)&Tbuf, (void*)&cand, (void*)&sortedBoxes,
        (void*)&rowmaj, (void*)&diagArr
    };
    hipLaunchCooperativeKernel((const void*)fused_proposal_kernel,
                               dim3(GRID_B), dim3(BLOCK_T), args, 0, stream);
}